// Round 21
// baseline (87.677 us; speedup 1.0000x reference)
//
#include <hip/hip_runtime.h>

#define EPSF 1e-10f
#define KPN 32
#define HH 96
#define WW 96
#define NPIX (HH*WW)     // 9216
#define CH 3
#define SH 128
#define SW 128
#define NIMG 64

__device__ inline float wred_sum(float v){
  #pragma unroll
  for(int off=32; off; off>>=1) v += __shfl_xor(v, off, 64);
  return v;
}
__device__ inline float wred_max(float v){
  #pragma unroll
  for(int off=32; off; off>>=1) v = fmaxf(v, __shfl_xor(v, off, 64));
  return v;
}

// ---------------- resize: jax.image.resize bilinear, antialias=True, 128->96 ----------------
__global__ __launch_bounds__(256) void k_resize(const float* __restrict__ img, float* __restrict__ out){
  int idx = blockIdx.x*256 + threadIdx.x;
  if (idx >= NIMG*CH*NPIX) return;
  int ox = idx % WW;
  int oy = (idx / WW) % HH;
  int nc = idx / NPIX;
  float xs = (ox + 0.5f)*(4.0f/3.0f) - 0.5f;
  float ys = (oy + 0.5f)*(4.0f/3.0f) - 0.5f;
  int jx0 = (int)ceilf(xs - 4.0f/3.0f);
  int jy0 = (int)ceilf(ys - 4.0f/3.0f);
  float wx[3], wy[3]; float sx=0.f, sy=0.f;
  #pragma unroll
  for(int t=0;t<3;t++){
    int j = jx0+t;
    float w = 1.0f - 0.75f*fabsf((float)j - xs);
    w = (j>=0 && j<SW) ? fmaxf(w,0.0f) : 0.0f;
    wx[t]=w; sx+=w;
    j = jy0+t;
    w = 1.0f - 0.75f*fabsf((float)j - ys);
    w = (j>=0 && j<SH) ? fmaxf(w,0.0f) : 0.0f;
    wy[t]=w; sy+=w;
  }
  float inv = 1.0f/(sx*sy);
  const float* base = img + (size_t)nc*SH*SW;
  float acc=0.f;
  #pragma unroll
  for(int ty=0;ty<3;ty++){
    if (wy[ty]==0.f) continue;
    int jy = min(max(jy0+ty,0), SH-1);
    #pragma unroll
    for(int tx=0;tx<3;tx++){
      if (wx[tx]==0.f) continue;
      int jx = min(max(jx0+tx,0), SW-1);
      acc += wy[ty]*wx[tx]*base[jy*SW+jx];
    }
  }
  out[idx] = acc*inv;
}

// ---------------- local entropy ----------------
// R20 shfl body + two latency levers (R20 showed: dep-chain bound, VALUBusy
// 35% @ 4.5 waves/SIMD, not atomics/spill/BW):
// 1) BIN-SPLIT x2 in a 512-thread block: hb=tid>>8 does bins hb*8..hb*8+7
//    (S,T are sums over bins -> exact split); upper half's partial S/T via
//    LDS (lane-contiguous, conflict-free); chain halves, waves double.
// 2) exp2-form: k_b = exp2(fma(beta, bf, a) + gamma*bf^2), a=-50*L2E*v^2,
//    beta=(100/15)*L2E*v -> 3 VALU/(pixel,bin) vs 5. Exact mod rounding;
//    OOB sentinel v=1e4 still underflows to +0.
__global__ __launch_bounds__(512) void k_entropy(const float* __restrict__ rimg, float* __restrict__ entC){
  __shared__ float SP[6][256], TP[6][256];
  int tid = threadIdx.x;
  int hb = tid >> 8;                    // bin half: 0 -> bins 0..7, 1 -> 8..15
  int l = tid & 255;
  int n = blockIdx.y;
  int ch = blockIdx.z;
  int wave = l >> 6, lane = l & 63;
  int half = lane >> 5, cl = lane & 31;
  int rp = wave*2 + half;               // 0..7 row-pair
  int r0 = blockIdx.x*16 + rp*2;        // output rows r0, r0+1
  int c0 = cl*3;                        // output cols c0..c0+2
  const float* src = rimg + ((size_t)(n*CH+ch))*NPIX;
  const float L2E = 1.4426950408889634f;
  const float GAM = -50.f*L2E/225.f;    // gamma
  float a[4][3], be[4][3];
  #pragma unroll
  for (int r=0;r<4;r++){
    int gr = r0-1+r;
    bool rok = (gr>=0 && gr<HH);
    #pragma unroll
    for (int c=0;c<3;c++){
      float v = rok ? src[gr*96 + c0 + c] : 1e4f;
      a[r][c]  = -50.f*L2E*v*v;
      be[r][c] = (100.f/15.f)*L2E*v;
    }
  }
  float S[2][3]={{0,0,0},{0,0,0}}, T[2][3]={{0,0,0},{0,0,0}};
  float bf0 = (float)(hb*8);
  #pragma unroll
  for (int b=0;b<8;b++){
    float bf = bf0 + (float)b;
    float cc = GAM*bf*bf;               // uniform per bin
    float k[4][3];
    #pragma unroll
    for (int r=0;r<4;r++)
      #pragma unroll
      for (int c=0;c<3;c++)
        k[r][c] = exp2f(__builtin_fmaf(be[r][c], bf, a[r][c]) + cc);
    #pragma unroll
    for (int o=0;o<2;o++){
      float cs0 = k[o][0]+k[o+1][0]+k[o+2][0];
      float cs1 = k[o][1]+k[o+1][1]+k[o+2][1];
      float cs2 = k[o][2]+k[o+1][2]+k[o+2][2];
      float lf = __shfl_up(cs2, 1, 64);  if (cl==0)  lf = 0.f;
      float rt = __shfl_down(cs0, 1, 64); if (cl==31) rt = 0.f;
      float p0 = (lf +cs0+cs1)*(1.f/9.f);
      float p1 = (cs0+cs1+cs2)*(1.f/9.f);
      float p2 = (cs1+cs2+rt )*(1.f/9.f);
      S[o][0]+=p0; T[o][0]+=p0*__logf(p0+EPSF);
      S[o][1]+=p1; T[o][1]+=p1*__logf(p1+EPSF);
      S[o][2]+=p2; T[o][2]+=p2*__logf(p2+EPSF);
    }
  }
  if (hb==1){
    #pragma unroll
    for (int o=0;o<2;o++)
      #pragma unroll
      for (int j=0;j<3;j++){
        SP[o*3+j][l] = S[o][j];
        TP[o*3+j][l] = T[o][j];
      }
  }
  __syncthreads();
  if (hb==0){
    float* dst = entC + ((size_t)(ch*NIMG + n))*NPIX;
    #pragma unroll
    for (int o=0;o<2;o++)
      #pragma unroll
      for (int j=0;j<3;j++){
        int i = o*3+j;
        float Ss = S[o][j] + SP[i][l];
        float Tt = T[o][j] + TP[i][l];
        float Sp = Ss+EPSF;
        dst[(size_t)(r0+o)*96 + (c0+j)] = (__logf(Sp) - Tt/Sp)*(1.f/3.f);
      }
  }
}

// ---------------- main gaussians pass (R20 exact — 44 us) ----------------
// s-split + XCD remap + asm depth-16 pipeline, dwordx4 loads; ent = sum of
// 3 per-channel planes at load time.
__global__ __launch_bounds__(256, 4) void k_main(const float* __restrict__ gauss,
                                              const float* __restrict__ status,
                                              const float* __restrict__ entC,
                                              float* __restrict__ miS,
                                              float* __restrict__ melN,
                                              float* __restrict__ mcelN,
                                              float* __restrict__ reS,
                                              float* __restrict__ ceS,
                                              unsigned int* __restrict__ gmax,
                                              float* __restrict__ hsG){
  __shared__ float stc[32], stq[32];
  int tid = threadIdx.x;
  int lane = tid & 63;
  int wgid = blockIdx.x;          // 0..575
  int xcd = wgid & 7;
  int q_ = wgid >> 3;             // 0..71
  int tile = q_ % 9;              // 0..8
  int n = xcd*8 + q_/9;           // 0..63
  int s = n & 3;
  int np = (s==0) ? n+3 : n-1;
  bool nz = (n==0);
  if (tid < 32) stc[tid] = status[n*32 + tid];
  else if (tid < 64) stq[tid-32] = status[np*32 + (tid-32)];
  __syncthreads();
  unsigned off = (unsigned)(tile*256 + tid);     // float4 index within a plane (2304/plane)
  const float4* __restrict__ gc = (const float4*)gauss + (size_t)n*32*2304 + off;
  const float4* __restrict__ gq = (const float4*)gauss + (size_t)np*32*2304 + off;
  const float4* __restrict__ ec = (const float4*)entC;
  float4 e0 = ec[(size_t)(0*NIMG + n)*2304 + off];
  float4 e1 = ec[(size_t)(1*NIMG + n)*2304 + off];
  float4 e2c = ec[(size_t)(2*NIMG + n)*2304 + off];
  float4 f0 = ec[(size_t)(0*NIMG + np)*2304 + off];
  float4 f1 = ec[(size_t)(1*NIMG + np)*2304 + off];
  float4 f2 = ec[(size_t)(2*NIMG + np)*2304 + off];
  float4 re2, se2;
  re2.x = e0.x+e1.x+e2c.x; re2.y = e0.y+e1.y+e2c.y; re2.z = e0.z+e1.z+e2c.z; re2.w = e0.w+e1.w+e2c.w;
  se2.x = f0.x+f1.x+f2.x;  se2.y = f0.y+f1.y+f2.y;  se2.z = f0.z+f1.z+f2.z;  se2.w = f0.w+f1.w+f2.w;
  float4 ce, K2;
  ce.x = fmaxf(re2.x, se2.x) - se2.x;  K2.x = fmaxf(se2.x - re2.x, 0.f);
  ce.y = fmaxf(re2.y, se2.y) - se2.y;  K2.y = fmaxf(se2.y - re2.y, 0.f);
  ce.z = fmaxf(re2.z, se2.z) - se2.z;  K2.z = fmaxf(se2.z - re2.z, 0.f);
  ce.w = fmaxf(re2.w, se2.w) - se2.w;  K2.w = fmaxf(se2.w - re2.w, 0.f);
  float4 am = make_float4(0,0,0,0), ag = make_float4(0,0,0,0), mi = make_float4(0,0,0,0);
  float hsacc = 0.f;
  float4 G[8], H[8];

#define GLD(dst, addr) asm volatile("global_load_dwordx4 %0, %1, off" : "=v"(dst) : "v"(addr) : "memory")
#define VMWAIT(N) asm volatile("s_waitcnt vmcnt(" #N ")" ::: "memory")

#define PC(g, h, CMP, sc, sp) { \
  float hm = fminf(fmaxf(__builtin_fmaf((g).CMP, 3.5f, -0.35f), 0.f), 1.f); \
  float hp = fminf(fmaxf(__builtin_fmaf((h).CMP, 3.5f, -0.35f), 0.f), 1.f); \
  hsl += hm; \
  float ah = (sc)*hm, sh = (sp)*hp; \
  am.CMP += ah; ag.CMP += (g).CMP; \
  float D = __builtin_fmaf(-se2.CMP, sh, K2.CMP); \
  mi.CMP += fminf((1.f - ah)*D, 0.f); }

#define PROC(g, h, KP) { \
  float sc = stc[KP], sp = stq[KP]; \
  float hsl = 0.f; \
  PC(g, h, x, sc, sp) PC(g, h, y, sc, sp) PC(g, h, z, sc, sp) PC(g, h, w, sc, sp) \
  if (nz && (KP)==0) hsacc = hsl; }

#define STEP(I, WN) { \
  VMWAIT(WN); \
  __builtin_amdgcn_sched_barrier(0); \
  PROC(G[(I)&7], H[(I)&7], (I)); \
  if ((I) < 24){ GLD(G[(I)&7], gc + ((I)+8)*2304); GLD(H[(I)&7], gq + ((I)+8)*2304); } \
}

  __builtin_amdgcn_sched_barrier(0);
  #pragma unroll
  for (int j=0;j<8;j++){ GLD(G[j], gc + j*2304); GLD(H[j], gq + j*2304); }

  STEP(0,14)  STEP(1,14)  STEP(2,14)  STEP(3,14)
  STEP(4,14)  STEP(5,14)  STEP(6,14)  STEP(7,14)
  STEP(8,14)  STEP(9,14)  STEP(10,14) STEP(11,14)
  STEP(12,14) STEP(13,14) STEP(14,14) STEP(15,14)
  STEP(16,14) STEP(17,14) STEP(18,14) STEP(19,14)
  STEP(20,14) STEP(21,14) STEP(22,14) STEP(23,14)
  STEP(24,14) STEP(25,12) STEP(26,10) STEP(27,8)
  STEP(28,6)  STEP(29,4)  STEP(30,2)  STEP(31,0)

#undef STEP
#undef PROC
#undef PC
#undef VMWAIT
#undef GLD

  float qx = 1.f - fminf(am.x, 1.f);
  float qy = 1.f - fminf(am.y, 1.f);
  float qz = 1.f - fminf(am.z, 1.f);
  float qw = 1.f - fminf(am.w, 1.f);
  float r1 = wred_sum(re2.x*qx + re2.y*qy + re2.z*qz + re2.w*qw);
  float r2 = wred_sum(ce.x*qx + ce.y*qy + ce.z*qz + ce.w*qw);
  float r3 = wred_sum(re2.x + re2.y + re2.z + re2.w);
  float r4 = wred_sum(ce.x + ce.y + ce.z + ce.w);
  float r5 = wred_max(fmaxf(fmaxf(ag.x, ag.y), fmaxf(ag.z, ag.w)));
  float r6 = wred_sum(mi.x + mi.y + mi.z + mi.w);
  if (lane==0){
    atomicAdd(&melN[n], r1);
    atomicAdd(&mcelN[n], r2);
    atomicAdd(&reS[n], r3);
    atomicAdd(&ceS[n], r4);
    atomicMax(&gmax[n], __float_as_uint(r5));
    atomicAdd(&miS[n], r6);
  }
  if (nz){
    float h = wred_sum(hsacc);
    if (lane==0) atomicAdd(hsG, h);
  }
}

// ---------------- finalization ----------------
__global__ __launch_bounds__(256) void k_final(const float* __restrict__ coords,
                                               const float* __restrict__ status,
                                               const float* __restrict__ miS,
                                               const float* __restrict__ melN,
                                               const float* __restrict__ mcelN,
                                               const float* __restrict__ reS,
                                               const float* __restrict__ ceS,
                                               const unsigned int* __restrict__ gmax,
                                               const float* __restrict__ hsG,
                                               float* __restrict__ out){
  __shared__ float wsum[4];
  int tid = threadIdx.x;
  int n = tid >> 2, q = tid & 3;   // n in 0..63, q selects 8 kp
  int s = n & 3;
  int np = (s==0) ? n+3 : n-1;
  float mc = 0.f, sl = 0.f;
  #pragma unroll
  for (int j=0;j<8;j++){
    int kp = q*8 + j;
    float dx = coords[(n*KPN+kp)*2+0] - coords[(np*KPN+kp)*2+0];
    float dy = coords[(n*KPN+kp)*2+1] - coords[(np*KPN+kp)*2+1];
    float st = status[n*KPN+kp];
    mc += sqrtf(dx*dx+dy*dy) * st * status[np*KPN+kp];
    sl += st;
  }
  mc += __shfl_xor(mc,1,64); mc += __shfl_xor(mc,2,64);
  sl += __shfl_xor(sl,1,64); sl += __shfl_xor(sl,2,64);
  float mint = 0.f;
  if (q==0){
    sl *= (1.f/KPN);
    float rsum = reS[n];
    float mel = melN[n]/(rsum+EPSF);
    float mcel = (s==0) ? 0.f : mcelN[n]/(ceS[n]+EPSF);
    // miS holds M = sum_px sum_kp min((1-ah)D, 0); full mi sum = 32*rsum + M
    // rc = (rsum - (32*rsum + M)/32)/hs = -M/(32*hs)
    float rc = (-miS[n]*(1.f/KPN)) / hsG[0];
    float itl = rc + 0.1f*mc;
    float ovl = fmaxf(__uint_as_float(gmax[n]) - 1.5f, 0.f)*(1.f/KPN);
    mint = 100.f*mel + 100.f*mcel + itl + 10.f*ovl + (1.f-mel)*2.5f*sl;
  }
  float r = wred_sum(mint);
  if ((tid&63)==0) wsum[tid>>6] = r;
  __syncthreads();
  if (tid==0) out[0] = (wsum[0]+wsum[1]+wsum[2]+wsum[3])*(1.f/64.f);
}

extern "C" void kernel_launch(void* const* d_in, const int* in_sizes, int n_in,
                              void* d_out, int out_size, void* d_ws, size_t ws_size,
                              hipStream_t stream){
  const float* coords = (const float*)d_in[0];
  const float* gauss  = (const float*)d_in[1];
  const float* status = (const float*)d_in[2];
  const float* images = (const float*)d_in[3];
  float* out = (float*)d_out;
  float* rimg = (float*)d_ws;                          // 1,769,472 f32
  float* entC = rimg + (size_t)NIMG*CH*NPIX;           // 3 x 589,824 f32
  float* miS  = entC + (size_t)CH*NIMG*NPIX;           // 64
  float* melN = miS + 64;
  float* mcelN = melN + 64;
  float* reS   = mcelN + 64;
  float* ceS   = reS + 64;
  unsigned int* gmax = (unsigned int*)(ceS + 64);      // 64
  float* hsG = (float*)(gmax + 64);                    // 1
  hipMemsetAsync(miS, 0, (6*64 + 1)*sizeof(float), stream);
  k_resize<<<(NIMG*CH*NPIX + 255)/256, 256, 0, stream>>>(images, rimg);
  k_entropy<<<dim3(6,64,3), 512, 0, stream>>>(rimg, entC);
  k_main<<<576, 256, 0, stream>>>(gauss, status, entC, miS, melN, mcelN, reS, ceS, gmax, hsG);
  k_final<<<1,256,0,stream>>>(coords, status, miS, melN, mcelN, reS, ceS, gmax, hsG, out);
}

// Round 22
// 86.979 us; speedup vs baseline: 1.0080x; 1.0080x over previous
//
#include <hip/hip_runtime.h>

#define EPSF 1e-10f
#define KPN 32
#define HH 96
#define WW 96
#define NPIX (HH*WW)     // 9216
#define CH 3
#define SH 128
#define SW 128
#define NIMG 64

__device__ inline float wred_sum(float v){
  #pragma unroll
  for(int off=32; off; off>>=1) v += __shfl_xor(v, off, 64);
  return v;
}
__device__ inline float wred_max(float v){
  #pragma unroll
  for(int off=32; off; off>>=1) v = fmaxf(v, __shfl_xor(v, off, 64));
  return v;
}

// ---------------- resize: jax.image.resize bilinear, antialias=True, 128->96 ----------------
__global__ __launch_bounds__(256) void k_resize(const float* __restrict__ img, float* __restrict__ out){
  int idx = blockIdx.x*256 + threadIdx.x;
  if (idx >= NIMG*CH*NPIX) return;
  int ox = idx % WW;
  int oy = (idx / WW) % HH;
  int nc = idx / NPIX;
  float xs = (ox + 0.5f)*(4.0f/3.0f) - 0.5f;
  float ys = (oy + 0.5f)*(4.0f/3.0f) - 0.5f;
  int jx0 = (int)ceilf(xs - 4.0f/3.0f);
  int jy0 = (int)ceilf(ys - 4.0f/3.0f);
  float wx[3], wy[3]; float sx=0.f, sy=0.f;
  #pragma unroll
  for(int t=0;t<3;t++){
    int j = jx0+t;
    float w = 1.0f - 0.75f*fabsf((float)j - xs);
    w = (j>=0 && j<SW) ? fmaxf(w,0.0f) : 0.0f;
    wx[t]=w; sx+=w;
    j = jy0+t;
    w = 1.0f - 0.75f*fabsf((float)j - ys);
    w = (j>=0 && j<SH) ? fmaxf(w,0.0f) : 0.0f;
    wy[t]=w; sy+=w;
  }
  float inv = 1.0f/(sx*sy);
  const float* base = img + (size_t)nc*SH*SW;
  float acc=0.f;
  #pragma unroll
  for(int ty=0;ty<3;ty++){
    if (wy[ty]==0.f) continue;
    int jy = min(max(jy0+ty,0), SH-1);
    #pragma unroll
    for(int tx=0;tx<3;tx++){
      if (wx[tx]==0.f) continue;
      int jx = min(max(jx0+tx,0), SW-1);
      acc += wy[ty]*wx[tx]*base[jy*SW+jx];
    }
  }
  out[idx] = acc*inv;
}

// ---------------- local entropy ----------------
// R20 body (256 threads, (256,2), shfl halo, per-channel planes, plain
// stores) with ONE unbundled change vs R21: exp2-form kernel eval only.
// k_b = exp2(fma(beta, bf, alpha) + gamma*bf^2), alpha=-50*L2E*v^2,
// beta=(100/15)*L2E*v, gamma=-50*L2E/225 -> 3 VALU/(pixel,bin) vs 5.
// (R21's bin-split/512-thread block regressed wall time — dropped.)
// OOB sentinel v=1e4: alpha ~ -7e9 -> exp2 underflows to +0.
__global__ __launch_bounds__(256, 2) void k_entropy(const float* __restrict__ rimg, float* __restrict__ entC){
  int tid = threadIdx.x;
  int n = blockIdx.y;
  int ch = blockIdx.z;
  int wave = tid >> 6, lane = tid & 63;
  int half = lane >> 5, cl = lane & 31;
  int rp = wave*2 + half;               // 0..7 row-pair within block
  int r0 = blockIdx.x*16 + rp*2;        // output rows r0, r0+1
  int c0 = cl*3;                        // output cols c0..c0+2
  const float* src = rimg + ((size_t)(n*CH+ch))*NPIX;
  const float L2E = 1.4426950408889634f;
  const float GAM = -50.f*L2E/225.f;
  float al[4][3], be[4][3];
  #pragma unroll
  for (int r=0;r<4;r++){
    int gr = r0-1+r;
    bool rok = (gr>=0 && gr<HH);
    #pragma unroll
    for (int c=0;c<3;c++){
      float v = rok ? src[gr*96 + c0 + c] : 1e4f;
      al[r][c] = -50.f*L2E*v*v;
      be[r][c] = (100.f/15.f)*L2E*v;
    }
  }
  float S[2][3]={{0,0,0},{0,0,0}}, T[2][3]={{0,0,0},{0,0,0}};
  #pragma unroll
  for (int b=0;b<16;b++){
    float bf = (float)b;
    float cc = GAM*bf*bf;               // uniform per bin
    float k[4][3];
    #pragma unroll
    for (int r=0;r<4;r++)
      #pragma unroll
      for (int c=0;c<3;c++)
        k[r][c] = exp2f(__builtin_fmaf(be[r][c], bf, al[r][c]) + cc);
    #pragma unroll
    for (int o=0;o<2;o++){
      float cs0 = k[o][0]+k[o+1][0]+k[o+2][0];
      float cs1 = k[o][1]+k[o+1][1]+k[o+2][1];
      float cs2 = k[o][2]+k[o+1][2]+k[o+2][2];
      float lf = __shfl_up(cs2, 1, 64);  if (cl==0)  lf = 0.f;
      float rt = __shfl_down(cs0, 1, 64); if (cl==31) rt = 0.f;
      float p0 = (lf +cs0+cs1)*(1.f/9.f);
      float p1 = (cs0+cs1+cs2)*(1.f/9.f);
      float p2 = (cs1+cs2+rt )*(1.f/9.f);
      S[o][0]+=p0; T[o][0]+=p0*__logf(p0+EPSF);
      S[o][1]+=p1; T[o][1]+=p1*__logf(p1+EPSF);
      S[o][2]+=p2; T[o][2]+=p2*__logf(p2+EPSF);
    }
  }
  float* dst = entC + ((size_t)(ch*NIMG + n))*NPIX;
  #pragma unroll
  for (int o=0;o<2;o++)
    #pragma unroll
    for (int j=0;j<3;j++){
      float Sp = S[o][j]+EPSF;
      float e = (__logf(Sp) - T[o][j]/Sp)*(1.f/3.f);
      dst[(size_t)(r0+o)*96 + (c0+j)] = e;
    }
}

// ---------------- main gaussians pass (R20 exact — 44 us) ----------------
// s-split + XCD remap + asm depth-16 pipeline, dwordx4 loads; ent = sum of
// 3 per-channel planes at load time.
__global__ __launch_bounds__(256, 4) void k_main(const float* __restrict__ gauss,
                                              const float* __restrict__ status,
                                              const float* __restrict__ entC,
                                              float* __restrict__ miS,
                                              float* __restrict__ melN,
                                              float* __restrict__ mcelN,
                                              float* __restrict__ reS,
                                              float* __restrict__ ceS,
                                              unsigned int* __restrict__ gmax,
                                              float* __restrict__ hsG){
  __shared__ float stc[32], stq[32];
  int tid = threadIdx.x;
  int lane = tid & 63;
  int wgid = blockIdx.x;          // 0..575
  int xcd = wgid & 7;
  int q_ = wgid >> 3;             // 0..71
  int tile = q_ % 9;              // 0..8
  int n = xcd*8 + q_/9;           // 0..63
  int s = n & 3;
  int np = (s==0) ? n+3 : n-1;
  bool nz = (n==0);
  if (tid < 32) stc[tid] = status[n*32 + tid];
  else if (tid < 64) stq[tid-32] = status[np*32 + (tid-32)];
  __syncthreads();
  unsigned off = (unsigned)(tile*256 + tid);     // float4 index within a plane (2304/plane)
  const float4* __restrict__ gc = (const float4*)gauss + (size_t)n*32*2304 + off;
  const float4* __restrict__ gq = (const float4*)gauss + (size_t)np*32*2304 + off;
  const float4* __restrict__ ec = (const float4*)entC;
  float4 e0 = ec[(size_t)(0*NIMG + n)*2304 + off];
  float4 e1 = ec[(size_t)(1*NIMG + n)*2304 + off];
  float4 e2c = ec[(size_t)(2*NIMG + n)*2304 + off];
  float4 f0 = ec[(size_t)(0*NIMG + np)*2304 + off];
  float4 f1 = ec[(size_t)(1*NIMG + np)*2304 + off];
  float4 f2 = ec[(size_t)(2*NIMG + np)*2304 + off];
  float4 re2, se2;
  re2.x = e0.x+e1.x+e2c.x; re2.y = e0.y+e1.y+e2c.y; re2.z = e0.z+e1.z+e2c.z; re2.w = e0.w+e1.w+e2c.w;
  se2.x = f0.x+f1.x+f2.x;  se2.y = f0.y+f1.y+f2.y;  se2.z = f0.z+f1.z+f2.z;  se2.w = f0.w+f1.w+f2.w;
  float4 ce, K2;
  ce.x = fmaxf(re2.x, se2.x) - se2.x;  K2.x = fmaxf(se2.x - re2.x, 0.f);
  ce.y = fmaxf(re2.y, se2.y) - se2.y;  K2.y = fmaxf(se2.y - re2.y, 0.f);
  ce.z = fmaxf(re2.z, se2.z) - se2.z;  K2.z = fmaxf(se2.z - re2.z, 0.f);
  ce.w = fmaxf(re2.w, se2.w) - se2.w;  K2.w = fmaxf(se2.w - re2.w, 0.f);
  float4 am = make_float4(0,0,0,0), ag = make_float4(0,0,0,0), mi = make_float4(0,0,0,0);
  float hsacc = 0.f;
  float4 G[8], H[8];

#define GLD(dst, addr) asm volatile("global_load_dwordx4 %0, %1, off" : "=v"(dst) : "v"(addr) : "memory")
#define VMWAIT(N) asm volatile("s_waitcnt vmcnt(" #N ")" ::: "memory")

#define PC(g, h, CMP, sc, sp) { \
  float hm = fminf(fmaxf(__builtin_fmaf((g).CMP, 3.5f, -0.35f), 0.f), 1.f); \
  float hp = fminf(fmaxf(__builtin_fmaf((h).CMP, 3.5f, -0.35f), 0.f), 1.f); \
  hsl += hm; \
  float ah = (sc)*hm, sh = (sp)*hp; \
  am.CMP += ah; ag.CMP += (g).CMP; \
  float D = __builtin_fmaf(-se2.CMP, sh, K2.CMP); \
  mi.CMP += fminf((1.f - ah)*D, 0.f); }

#define PROC(g, h, KP) { \
  float sc = stc[KP], sp = stq[KP]; \
  float hsl = 0.f; \
  PC(g, h, x, sc, sp) PC(g, h, y, sc, sp) PC(g, h, z, sc, sp) PC(g, h, w, sc, sp) \
  if (nz && (KP)==0) hsacc = hsl; }

#define STEP(I, WN) { \
  VMWAIT(WN); \
  __builtin_amdgcn_sched_barrier(0); \
  PROC(G[(I)&7], H[(I)&7], (I)); \
  if ((I) < 24){ GLD(G[(I)&7], gc + ((I)+8)*2304); GLD(H[(I)&7], gq + ((I)+8)*2304); } \
}

  __builtin_amdgcn_sched_barrier(0);
  #pragma unroll
  for (int j=0;j<8;j++){ GLD(G[j], gc + j*2304); GLD(H[j], gq + j*2304); }

  STEP(0,14)  STEP(1,14)  STEP(2,14)  STEP(3,14)
  STEP(4,14)  STEP(5,14)  STEP(6,14)  STEP(7,14)
  STEP(8,14)  STEP(9,14)  STEP(10,14) STEP(11,14)
  STEP(12,14) STEP(13,14) STEP(14,14) STEP(15,14)
  STEP(16,14) STEP(17,14) STEP(18,14) STEP(19,14)
  STEP(20,14) STEP(21,14) STEP(22,14) STEP(23,14)
  STEP(24,14) STEP(25,12) STEP(26,10) STEP(27,8)
  STEP(28,6)  STEP(29,4)  STEP(30,2)  STEP(31,0)

#undef STEP
#undef PROC
#undef PC
#undef VMWAIT
#undef GLD

  float qx = 1.f - fminf(am.x, 1.f);
  float qy = 1.f - fminf(am.y, 1.f);
  float qz = 1.f - fminf(am.z, 1.f);
  float qw = 1.f - fminf(am.w, 1.f);
  float r1 = wred_sum(re2.x*qx + re2.y*qy + re2.z*qz + re2.w*qw);
  float r2 = wred_sum(ce.x*qx + ce.y*qy + ce.z*qz + ce.w*qw);
  float r3 = wred_sum(re2.x + re2.y + re2.z + re2.w);
  float r4 = wred_sum(ce.x + ce.y + ce.z + ce.w);
  float r5 = wred_max(fmaxf(fmaxf(ag.x, ag.y), fmaxf(ag.z, ag.w)));
  float r6 = wred_sum(mi.x + mi.y + mi.z + mi.w);
  if (lane==0){
    atomicAdd(&melN[n], r1);
    atomicAdd(&mcelN[n], r2);
    atomicAdd(&reS[n], r3);
    atomicAdd(&ceS[n], r4);
    atomicMax(&gmax[n], __float_as_uint(r5));
    atomicAdd(&miS[n], r6);
  }
  if (nz){
    float h = wred_sum(hsacc);
    if (lane==0) atomicAdd(hsG, h);
  }
}

// ---------------- finalization ----------------
__global__ __launch_bounds__(256) void k_final(const float* __restrict__ coords,
                                               const float* __restrict__ status,
                                               const float* __restrict__ miS,
                                               const float* __restrict__ melN,
                                               const float* __restrict__ mcelN,
                                               const float* __restrict__ reS,
                                               const float* __restrict__ ceS,
                                               const unsigned int* __restrict__ gmax,
                                               const float* __restrict__ hsG,
                                               float* __restrict__ out){
  __shared__ float wsum[4];
  int tid = threadIdx.x;
  int n = tid >> 2, q = tid & 3;   // n in 0..63, q selects 8 kp
  int s = n & 3;
  int np = (s==0) ? n+3 : n-1;
  float mc = 0.f, sl = 0.f;
  #pragma unroll
  for (int j=0;j<8;j++){
    int kp = q*8 + j;
    float dx = coords[(n*KPN+kp)*2+0] - coords[(np*KPN+kp)*2+0];
    float dy = coords[(n*KPN+kp)*2+1] - coords[(np*KPN+kp)*2+1];
    float st = status[n*KPN+kp];
    mc += sqrtf(dx*dx+dy*dy) * st * status[np*KPN+kp];
    sl += st;
  }
  mc += __shfl_xor(mc,1,64); mc += __shfl_xor(mc,2,64);
  sl += __shfl_xor(sl,1,64); sl += __shfl_xor(sl,2,64);
  float mint = 0.f;
  if (q==0){
    sl *= (1.f/KPN);
    float rsum = reS[n];
    float mel = melN[n]/(rsum+EPSF);
    float mcel = (s==0) ? 0.f : mcelN[n]/(ceS[n]+EPSF);
    // miS holds M = sum_px sum_kp min((1-ah)D, 0); full mi sum = 32*rsum + M
    // rc = (rsum - (32*rsum + M)/32)/hs = -M/(32*hs)
    float rc = (-miS[n]*(1.f/KPN)) / hsG[0];
    float itl = rc + 0.1f*mc;
    float ovl = fmaxf(__uint_as_float(gmax[n]) - 1.5f, 0.f)*(1.f/KPN);
    mint = 100.f*mel + 100.f*mcel + itl + 10.f*ovl + (1.f-mel)*2.5f*sl;
  }
  float r = wred_sum(mint);
  if ((tid&63)==0) wsum[tid>>6] = r;
  __syncthreads();
  if (tid==0) out[0] = (wsum[0]+wsum[1]+wsum[2]+wsum[3])*(1.f/64.f);
}

extern "C" void kernel_launch(void* const* d_in, const int* in_sizes, int n_in,
                              void* d_out, int out_size, void* d_ws, size_t ws_size,
                              hipStream_t stream){
  const float* coords = (const float*)d_in[0];
  const float* gauss  = (const float*)d_in[1];
  const float* status = (const float*)d_in[2];
  const float* images = (const float*)d_in[3];
  float* out = (float*)d_out;
  float* rimg = (float*)d_ws;                          // 1,769,472 f32
  float* entC = rimg + (size_t)NIMG*CH*NPIX;           // 3 x 589,824 f32
  float* miS  = entC + (size_t)CH*NIMG*NPIX;           // 64
  float* melN = miS + 64;
  float* mcelN = melN + 64;
  float* reS   = mcelN + 64;
  float* ceS   = reS + 64;
  unsigned int* gmax = (unsigned int*)(ceS + 64);      // 64
  float* hsG = (float*)(gmax + 64);                    // 1
  hipMemsetAsync(miS, 0, (6*64 + 1)*sizeof(float), stream);
  k_resize<<<(NIMG*CH*NPIX + 255)/256, 256, 0, stream>>>(images, rimg);
  k_entropy<<<dim3(6,64,3), 256, 0, stream>>>(rimg, entC);
  k_main<<<576, 256, 0, stream>>>(gauss, status, entC, miS, melN, mcelN, reS, ceS, gmax, hsG);
  k_final<<<1,256,0,stream>>>(coords, status, miS, melN, mcelN, reS, ceS, gmax, hsG, out);
}

// Round 23
// 83.525 us; speedup vs baseline: 1.0497x; 1.0414x over previous
//
#include <hip/hip_runtime.h>

#define EPSF 1e-10f
#define KPN 32
#define HH 96
#define WW 96
#define NPIX (HH*WW)     // 9216
#define CH 3
#define SH 128
#define SW 128
#define NIMG 64

__device__ inline float wred_sum(float v){
  #pragma unroll
  for(int off=32; off; off>>=1) v += __shfl_xor(v, off, 64);
  return v;
}
__device__ inline float wred_max(float v){
  #pragma unroll
  for(int off=32; off; off>>=1) v = fmaxf(v, __shfl_xor(v, off, 64));
  return v;
}

// ---------------- resize: jax.image.resize bilinear, antialias=True, 128->96 ----------------
__global__ __launch_bounds__(256) void k_resize(const float* __restrict__ img, float* __restrict__ out){
  int idx = blockIdx.x*256 + threadIdx.x;
  if (idx >= NIMG*CH*NPIX) return;
  int ox = idx % WW;
  int oy = (idx / WW) % HH;
  int nc = idx / NPIX;
  float xs = (ox + 0.5f)*(4.0f/3.0f) - 0.5f;
  float ys = (oy + 0.5f)*(4.0f/3.0f) - 0.5f;
  int jx0 = (int)ceilf(xs - 4.0f/3.0f);
  int jy0 = (int)ceilf(ys - 4.0f/3.0f);
  float wx[3], wy[3]; float sx=0.f, sy=0.f;
  #pragma unroll
  for(int t=0;t<3;t++){
    int j = jx0+t;
    float w = 1.0f - 0.75f*fabsf((float)j - xs);
    w = (j>=0 && j<SW) ? fmaxf(w,0.0f) : 0.0f;
    wx[t]=w; sx+=w;
    j = jy0+t;
    float w2 = 1.0f - 0.75f*fabsf((float)j - ys);
    w2 = (j>=0 && j<SH) ? fmaxf(w2,0.0f) : 0.0f;
    wy[t]=w2; sy+=w2;
  }
  float inv = 1.0f/(sx*sy);
  const float* base = img + (size_t)nc*SH*SW;
  float acc=0.f;
  #pragma unroll
  for(int ty=0;ty<3;ty++){
    if (wy[ty]==0.f) continue;
    int jy = min(max(jy0+ty,0), SH-1);
    #pragma unroll
    for(int tx=0;tx<3;tx++){
      if (wx[tx]==0.f) continue;
      int jx = min(max(jx0+tx,0), SW-1);
      acc += wy[ty]*wx[tx]*base[jy*SW+jx];
    }
  }
  out[idx] = acc*inv;
}

// ---------------- local entropy (R20 exact — best measured) ----------------
// Channel-split (grid z = ch). Lane owns 3 output cols x 2 output rows
// (4x3 reg halo); horizontal 3-tap shared across lanes via shfl (edge lanes
// masked = zero-pad). Per-channel output planes + plain stores (single
// writer per element; R18's atomic variant had 20.7MB of coherence-point
// RMW traffic but identical wall time). VGPR 64, no spill. ~34us timed:
// dependency-latency-bound; six restructurings (2x1 retile, fused-768,
// bin-split-512, even/odd pairing, exp2-form, shfl-free) all regressed.
__global__ __launch_bounds__(256, 2) void k_entropy(const float* __restrict__ rimg, float* __restrict__ entC){
  int tid = threadIdx.x;
  int n = blockIdx.y;
  int ch = blockIdx.z;
  int wave = tid >> 6, lane = tid & 63;
  int half = lane >> 5, cl = lane & 31;
  int rp = wave*2 + half;               // 0..7 row-pair within block
  int r0 = blockIdx.x*16 + rp*2;        // output rows r0, r0+1
  int c0 = cl*3;                        // output cols c0..c0+2
  const float* src = rimg + ((size_t)(n*CH+ch))*NPIX;
  float v[4][3];
  #pragma unroll
  for (int r=0;r<4;r++){
    int gr = r0-1+r;
    bool rok = (gr>=0 && gr<HH);
    #pragma unroll
    for (int c=0;c<3;c++){
      v[r][c] = rok ? src[gr*96 + c0 + c] : 1e4f;
    }
  }
  float S[2][3]={{0,0,0},{0,0,0}}, T[2][3]={{0,0,0},{0,0,0}};
  #pragma unroll
  for (int b=0;b<16;b++){
    float cb = (float)b * (1.0f/15.0f);
    float k[4][3];
    #pragma unroll
    for (int r=0;r<4;r++)
      #pragma unroll
      for (int c=0;c<3;c++){
        float d = v[r][c] - cb;
        k[r][c] = __expf(-50.f*d*d);
      }
    #pragma unroll
    for (int o=0;o<2;o++){
      float cs0 = k[o][0]+k[o+1][0]+k[o+2][0];
      float cs1 = k[o][1]+k[o+1][1]+k[o+2][1];
      float cs2 = k[o][2]+k[o+1][2]+k[o+2][2];
      float lf = __shfl_up(cs2, 1, 64);  if (cl==0)  lf = 0.f;
      float rt = __shfl_down(cs0, 1, 64); if (cl==31) rt = 0.f;
      float p0 = (lf +cs0+cs1)*(1.f/9.f);
      float p1 = (cs0+cs1+cs2)*(1.f/9.f);
      float p2 = (cs1+cs2+rt )*(1.f/9.f);
      S[o][0]+=p0; T[o][0]+=p0*__logf(p0+EPSF);
      S[o][1]+=p1; T[o][1]+=p1*__logf(p1+EPSF);
      S[o][2]+=p2; T[o][2]+=p2*__logf(p2+EPSF);
    }
  }
  float* dst = entC + ((size_t)(ch*NIMG + n))*NPIX;
  #pragma unroll
  for (int o=0;o<2;o++)
    #pragma unroll
    for (int j=0;j<3;j++){
      float Sp = S[o][j]+EPSF;
      float e = (__logf(Sp) - T[o][j]/Sp)*(1.f/3.f);
      dst[(size_t)(r0+o)*96 + (c0+j)] = e;
    }
}

// ---------------- main gaussians pass (R20 exact — 44 us) ----------------
// s-split + XCD remap + asm depth-16 pipeline, dwordx4 loads; ent = sum of
// 3 per-channel planes at load time. 44us = per-CU load-instruction service
// limit (~115cy/load-inst, invariant across ILP/TLP/asm/XCD experiments;
// dwordx2->dwordx4 was the one lever that moved it, 55->44).
__global__ __launch_bounds__(256, 4) void k_main(const float* __restrict__ gauss,
                                              const float* __restrict__ status,
                                              const float* __restrict__ entC,
                                              float* __restrict__ miS,
                                              float* __restrict__ melN,
                                              float* __restrict__ mcelN,
                                              float* __restrict__ reS,
                                              float* __restrict__ ceS,
                                              unsigned int* __restrict__ gmax,
                                              float* __restrict__ hsG){
  __shared__ float stc[32], stq[32];
  int tid = threadIdx.x;
  int lane = tid & 63;
  int wgid = blockIdx.x;          // 0..575
  int xcd = wgid & 7;
  int q_ = wgid >> 3;             // 0..71
  int tile = q_ % 9;              // 0..8
  int n = xcd*8 + q_/9;           // 0..63
  int s = n & 3;
  int np = (s==0) ? n+3 : n-1;
  bool nz = (n==0);
  if (tid < 32) stc[tid] = status[n*32 + tid];
  else if (tid < 64) stq[tid-32] = status[np*32 + (tid-32)];
  __syncthreads();
  unsigned off = (unsigned)(tile*256 + tid);     // float4 index within a plane (2304/plane)
  const float4* __restrict__ gc = (const float4*)gauss + (size_t)n*32*2304 + off;
  const float4* __restrict__ gq = (const float4*)gauss + (size_t)np*32*2304 + off;
  const float4* __restrict__ ec = (const float4*)entC;
  float4 e0 = ec[(size_t)(0*NIMG + n)*2304 + off];
  float4 e1 = ec[(size_t)(1*NIMG + n)*2304 + off];
  float4 e2c = ec[(size_t)(2*NIMG + n)*2304 + off];
  float4 f0 = ec[(size_t)(0*NIMG + np)*2304 + off];
  float4 f1 = ec[(size_t)(1*NIMG + np)*2304 + off];
  float4 f2 = ec[(size_t)(2*NIMG + np)*2304 + off];
  float4 re2, se2;
  re2.x = e0.x+e1.x+e2c.x; re2.y = e0.y+e1.y+e2c.y; re2.z = e0.z+e1.z+e2c.z; re2.w = e0.w+e1.w+e2c.w;
  se2.x = f0.x+f1.x+f2.x;  se2.y = f0.y+f1.y+f2.y;  se2.z = f0.z+f1.z+f2.z;  se2.w = f0.w+f1.w+f2.w;
  float4 ce, K2;
  ce.x = fmaxf(re2.x, se2.x) - se2.x;  K2.x = fmaxf(se2.x - re2.x, 0.f);
  ce.y = fmaxf(re2.y, se2.y) - se2.y;  K2.y = fmaxf(se2.y - re2.y, 0.f);
  ce.z = fmaxf(re2.z, se2.z) - se2.z;  K2.z = fmaxf(se2.z - re2.z, 0.f);
  ce.w = fmaxf(re2.w, se2.w) - se2.w;  K2.w = fmaxf(se2.w - re2.w, 0.f);
  float4 am = make_float4(0,0,0,0), ag = make_float4(0,0,0,0), mi = make_float4(0,0,0,0);
  float hsacc = 0.f;
  float4 G[8], H[8];

#define GLD(dst, addr) asm volatile("global_load_dwordx4 %0, %1, off" : "=v"(dst) : "v"(addr) : "memory")
#define VMWAIT(N) asm volatile("s_waitcnt vmcnt(" #N ")" ::: "memory")

#define PC(g, h, CMP, sc, sp) { \
  float hm = fminf(fmaxf(__builtin_fmaf((g).CMP, 3.5f, -0.35f), 0.f), 1.f); \
  float hp = fminf(fmaxf(__builtin_fmaf((h).CMP, 3.5f, -0.35f), 0.f), 1.f); \
  hsl += hm; \
  float ah = (sc)*hm, sh = (sp)*hp; \
  am.CMP += ah; ag.CMP += (g).CMP; \
  float D = __builtin_fmaf(-se2.CMP, sh, K2.CMP); \
  mi.CMP += fminf((1.f - ah)*D, 0.f); }

#define PROC(g, h, KP) { \
  float sc = stc[KP], sp = stq[KP]; \
  float hsl = 0.f; \
  PC(g, h, x, sc, sp) PC(g, h, y, sc, sp) PC(g, h, z, sc, sp) PC(g, h, w, sc, sp) \
  if (nz && (KP)==0) hsacc = hsl; }

#define STEP(I, WN) { \
  VMWAIT(WN); \
  __builtin_amdgcn_sched_barrier(0); \
  PROC(G[(I)&7], H[(I)&7], (I)); \
  if ((I) < 24){ GLD(G[(I)&7], gc + ((I)+8)*2304); GLD(H[(I)&7], gq + ((I)+8)*2304); } \
}

  __builtin_amdgcn_sched_barrier(0);
  #pragma unroll
  for (int j=0;j<8;j++){ GLD(G[j], gc + j*2304); GLD(H[j], gq + j*2304); }

  STEP(0,14)  STEP(1,14)  STEP(2,14)  STEP(3,14)
  STEP(4,14)  STEP(5,14)  STEP(6,14)  STEP(7,14)
  STEP(8,14)  STEP(9,14)  STEP(10,14) STEP(11,14)
  STEP(12,14) STEP(13,14) STEP(14,14) STEP(15,14)
  STEP(16,14) STEP(17,14) STEP(18,14) STEP(19,14)
  STEP(20,14) STEP(21,14) STEP(22,14) STEP(23,14)
  STEP(24,14) STEP(25,12) STEP(26,10) STEP(27,8)
  STEP(28,6)  STEP(29,4)  STEP(30,2)  STEP(31,0)

#undef STEP
#undef PROC
#undef PC
#undef VMWAIT
#undef GLD

  float qx = 1.f - fminf(am.x, 1.f);
  float qy = 1.f - fminf(am.y, 1.f);
  float qz = 1.f - fminf(am.z, 1.f);
  float qw = 1.f - fminf(am.w, 1.f);
  float r1 = wred_sum(re2.x*qx + re2.y*qy + re2.z*qz + re2.w*qw);
  float r2 = wred_sum(ce.x*qx + ce.y*qy + ce.z*qz + ce.w*qw);
  float r3 = wred_sum(re2.x + re2.y + re2.z + re2.w);
  float r4 = wred_sum(ce.x + ce.y + ce.z + ce.w);
  float r5 = wred_max(fmaxf(fmaxf(ag.x, ag.y), fmaxf(ag.z, ag.w)));
  float r6 = wred_sum(mi.x + mi.y + mi.z + mi.w);
  if (lane==0){
    atomicAdd(&melN[n], r1);
    atomicAdd(&mcelN[n], r2);
    atomicAdd(&reS[n], r3);
    atomicAdd(&ceS[n], r4);
    atomicMax(&gmax[n], __float_as_uint(r5));
    atomicAdd(&miS[n], r6);
  }
  if (nz){
    float h = wred_sum(hsacc);
    if (lane==0) atomicAdd(hsG, h);
  }
}

// ---------------- finalization ----------------
__global__ __launch_bounds__(256) void k_final(const float* __restrict__ coords,
                                               const float* __restrict__ status,
                                               const float* __restrict__ miS,
                                               const float* __restrict__ melN,
                                               const float* __restrict__ mcelN,
                                               const float* __restrict__ reS,
                                               const float* __restrict__ ceS,
                                               const unsigned int* __restrict__ gmax,
                                               const float* __restrict__ hsG,
                                               float* __restrict__ out){
  __shared__ float wsum[4];
  int tid = threadIdx.x;
  int n = tid >> 2, q = tid & 3;   // n in 0..63, q selects 8 kp
  int s = n & 3;
  int np = (s==0) ? n+3 : n-1;
  float mc = 0.f, sl = 0.f;
  #pragma unroll
  for (int j=0;j<8;j++){
    int kp = q*8 + j;
    float dx = coords[(n*KPN+kp)*2+0] - coords[(np*KPN+kp)*2+0];
    float dy = coords[(n*KPN+kp)*2+1] - coords[(np*KPN+kp)*2+1];
    float st = status[n*KPN+kp];
    mc += sqrtf(dx*dx+dy*dy) * st * status[np*KPN+kp];
    sl += st;
  }
  mc += __shfl_xor(mc,1,64); mc += __shfl_xor(mc,2,64);
  sl += __shfl_xor(sl,1,64); sl += __shfl_xor(sl,2,64);
  float mint = 0.f;
  if (q==0){
    sl *= (1.f/KPN);
    float rsum = reS[n];
    float mel = melN[n]/(rsum+EPSF);
    float mcel = (s==0) ? 0.f : mcelN[n]/(ceS[n]+EPSF);
    // miS holds M = sum_px sum_kp min((1-ah)D, 0); full mi sum = 32*rsum + M
    // rc = (rsum - (32*rsum + M)/32)/hs = -M/(32*hs)
    float rc = (-miS[n]*(1.f/KPN)) / hsG[0];
    float itl = rc + 0.1f*mc;
    float ovl = fmaxf(__uint_as_float(gmax[n]) - 1.5f, 0.f)*(1.f/KPN);
    mint = 100.f*mel + 100.f*mcel + itl + 10.f*ovl + (1.f-mel)*2.5f*sl;
  }
  float r = wred_sum(mint);
  if ((tid&63)==0) wsum[tid>>6] = r;
  __syncthreads();
  if (tid==0) out[0] = (wsum[0]+wsum[1]+wsum[2]+wsum[3])*(1.f/64.f);
}

extern "C" void kernel_launch(void* const* d_in, const int* in_sizes, int n_in,
                              void* d_out, int out_size, void* d_ws, size_t ws_size,
                              hipStream_t stream){
  const float* coords = (const float*)d_in[0];
  const float* gauss  = (const float*)d_in[1];
  const float* status = (const float*)d_in[2];
  const float* images = (const float*)d_in[3];
  float* out = (float*)d_out;
  float* rimg = (float*)d_ws;                          // 1,769,472 f32
  float* entC = rimg + (size_t)NIMG*CH*NPIX;           // 3 x 589,824 f32
  float* miS  = entC + (size_t)CH*NIMG*NPIX;           // 64
  float* melN = miS + 64;
  float* mcelN = melN + 64;
  float* reS   = mcelN + 64;
  float* ceS   = reS + 64;
  unsigned int* gmax = (unsigned int*)(ceS + 64);      // 64
  float* hsG = (float*)(gmax + 64);                    // 1
  hipMemsetAsync(miS, 0, (6*64 + 1)*sizeof(float), stream);
  k_resize<<<(NIMG*CH*NPIX + 255)/256, 256, 0, stream>>>(images, rimg);
  k_entropy<<<dim3(6,64,3), 256, 0, stream>>>(rimg, entC);
  k_main<<<576, 256, 0, stream>>>(gauss, status, entC, miS, melN, mcelN, reS, ceS, gmax, hsG);
  k_final<<<1,256,0,stream>>>(coords, status, miS, melN, mcelN, reS, ceS, gmax, hsG, out);
}